// Round 7
// baseline (83.128 us; speedup 1.0000x reference)
//
#include <hip/hip_runtime.h>
#include <hip/hip_bf16.h>

typedef __attribute__((ext_vector_type(8))) short bf16x8;
typedef __attribute__((ext_vector_type(4))) float f32x4;

typedef const __attribute__((address_space(1))) void* gptr_t;
typedef __attribute__((address_space(3))) void* lptr_t;

#define NROW 8192
#define DDIM 256
#define HALF_B 4096
#define NB 64                        // 8192/128 tile bands
#define NTILES (NB * (NB + 1) / 2)   // 2080 upper-triangle tiles

// exp(dot/T) = exp2(dot * log2(e)/T), T = 0.07
#define E2SCALE 20.6099291555566196f
#define INV_T   14.2857142857142858f

// ---------------- kernel 1: row-normalize + bf16 cast + zero P/loss ---------
__global__ __launch_bounds__(256) void normalize_kernel(
    const float* __restrict__ z_i, const float* __restrict__ z_j,
    __hip_bfloat16* __restrict__ zn, float4* __restrict__ P4,
    float* __restrict__ loss_accum) {
  const int lane = threadIdx.x & 63;
  const int w = blockIdx.x * 4 + (threadIdx.x >> 6);  // wave id 0..2047
  for (int row = w; row < NROW; row += 2048) {
    const float* src = (row < HALF_B) ? (z_i + (size_t)row * DDIM)
                                      : (z_j + (size_t)(row - HALF_B) * DDIM);
    float4 v = *reinterpret_cast<const float4*>(src + lane * 4);
    float ss = v.x * v.x + v.y * v.y + v.z * v.z + v.w * v.w;
#pragma unroll
    for (int m = 32; m; m >>= 1) ss += __shfl_xor(ss, m);
    float inv = 1.0f / sqrtf(ss);
    ushort4 o;
    {
      __hip_bfloat16 h;
      h = __float2bfloat16(v.x * inv); o.x = *reinterpret_cast<unsigned short*>(&h);
      h = __float2bfloat16(v.y * inv); o.y = *reinterpret_cast<unsigned short*>(&h);
      h = __float2bfloat16(v.z * inv); o.z = *reinterpret_cast<unsigned short*>(&h);
      h = __float2bfloat16(v.w * inv); o.w = *reinterpret_cast<unsigned short*>(&h);
    }
    *reinterpret_cast<ushort4*>(zn + (size_t)row * DDIM + lane * 4) = o;
  }
  // zero P (64 x 8192 f32 = 131072 float4) with 131072 threads
  const int t = blockIdx.x * 256 + threadIdx.x;
  P4[t] = float4{0.0f, 0.0f, 0.0f, 0.0f};
  if (t == 0) *loss_accum = 0.0f;
}

// ======== shared main-loop macro bits for gram kernels ========
// 512 thr = 8 waves (2 row x 4 col), wave-tile 64x32 (acc[4][2]).
// LDS double-buffered; 2-phase: stage(kt+1) issued BEFORE compute(kt),
// ONE barrier per kt. XOR-swizzle both sides.

// ---------------- kernel 2a: ABLATION — main loop only ----------------------
__global__ __launch_bounds__(512, 4) void gram_abl_kernel(
    const __hip_bfloat16* __restrict__ zn) {
  __shared__ __hip_bfloat16 Asm[2][128 * 64];
  __shared__ __hip_bfloat16 Bsm[2][128 * 64];

  const int tid = threadIdx.x;
  const int lane = tid & 63;
  const int wid = tid >> 6;
  const int wr = wid >> 2;
  const int wc = wid & 3;

  int p = blockIdx.x;
  int by = 0;
  while (p >= NB - by) { p -= NB - by; ++by; }
  const int bx = by + p;
  const int rowBase = by * 128;
  const int colBase = bx * 128;

  f32x4 acc[4][2] = {};
  const int csw = ((tid & 7) ^ ((tid >> 3) & 7)) * 8;
  const int rloc = tid >> 3;

  auto stage = [&](int kt, int b) {
#pragma unroll
    for (int t = 0; t < 2; ++t) {
      const int r = t * 64 + rloc;
      const __hip_bfloat16* ga = zn + (size_t)(rowBase + r) * DDIM + kt * 64 + csw;
      const __hip_bfloat16* gb = zn + (size_t)(colBase + r) * DDIM + kt * 64 + csw;
      char* lA = reinterpret_cast<char*>(Asm) + b * 16384 + t * 8192 + wid * 1024;
      char* lB = reinterpret_cast<char*>(Bsm) + b * 16384 + t * 8192 + wid * 1024;
      __builtin_amdgcn_global_load_lds((gptr_t)ga, (lptr_t)lA, 16, 0, 0);
      __builtin_amdgcn_global_load_lds((gptr_t)gb, (lptr_t)lB, 16, 0, 0);
    }
  };

  stage(0, 0);
  __syncthreads();
  const int xorv = (lane & 7) << 4;
  for (int kt = 0; kt < 4; ++kt) {
    if (kt < 3) stage(kt + 1, (kt + 1) & 1);
    const char* Ab = reinterpret_cast<const char*>(Asm) + (kt & 1) * 16384;
    const char* Bb = reinterpret_cast<const char*>(Bsm) + (kt & 1) * 16384;
#pragma unroll
    for (int kk = 0; kk < 2; ++kk) {
      bf16x8 af[4], bfr[2];
      const int kcolb = (kk * 32 + (lane >> 4) * 8) * 2;
      const int arow = wr * 64 + (lane & 15);
      const int brow = wc * 32 + (lane & 15);
#pragma unroll
      for (int m = 0; m < 4; ++m)
        af[m] = *reinterpret_cast<const bf16x8*>(
            Ab + ((((arow + m * 16) << 7) + kcolb) ^ xorv));
#pragma unroll
      for (int n = 0; n < 2; ++n)
        bfr[n] = *reinterpret_cast<const bf16x8*>(
            Bb + ((((brow + n * 16) << 7) + kcolb) ^ xorv));
#pragma unroll
      for (int m = 0; m < 4; ++m)
#pragma unroll
        for (int n = 0; n < 2; ++n)
          acc[m][n] = __builtin_amdgcn_mfma_f32_16x16x32_bf16(
              af[m], bfr[n], acc[m][n], 0, 0, 0);
    }
    __syncthreads();
  }

  // keep-alive (rule #17): prevent DCE of mfma/ds_read/stage chain; no writes
#pragma unroll
  for (int m = 0; m < 4; ++m)
#pragma unroll
    for (int n = 0; n < 2; ++n) {
      asm volatile("" :: "v"(acc[m][n][0]), "v"(acc[m][n][1]),
                         "v"(acc[m][n][2]), "v"(acc[m][n][3]));
    }
}

// ---------------- kernel 2b: REAL gram — dbuf main loop + epilogue ----------
__global__ __launch_bounds__(512, 4) void gram_kernel(
    const __hip_bfloat16* __restrict__ zn,
    float* __restrict__ P, float* __restrict__ pos) {
  __shared__ __hip_bfloat16 Asm[2][128 * 64];
  __shared__ __hip_bfloat16 Bsm[2][128 * 64];
  __shared__ float rowbuf[128];
  __shared__ float colbuf[128];

  const int tid = threadIdx.x;
  const int lane = tid & 63;
  const int wid = tid >> 6;
  const int wr = wid >> 2;
  const int wc = wid & 3;

  int p = blockIdx.x;
  int by = 0;
  while (p >= NB - by) { p -= NB - by; ++by; }
  const int bx = by + p;
  const int rowBase = by * 128;
  const int colBase = bx * 128;
  const bool isdiag = (bx == by);
  const bool ispos = (bx - by == 32);

  if (tid < 128) rowbuf[tid] = 0.0f;
  else if (tid < 256) colbuf[tid - 128] = 0.0f;

  f32x4 acc[4][2] = {};
  const int csw = ((tid & 7) ^ ((tid >> 3) & 7)) * 8;
  const int rloc = tid >> 3;

  auto stage = [&](int kt, int b) {
#pragma unroll
    for (int t = 0; t < 2; ++t) {
      const int r = t * 64 + rloc;
      const __hip_bfloat16* ga = zn + (size_t)(rowBase + r) * DDIM + kt * 64 + csw;
      const __hip_bfloat16* gb = zn + (size_t)(colBase + r) * DDIM + kt * 64 + csw;
      char* lA = reinterpret_cast<char*>(Asm) + b * 16384 + t * 8192 + wid * 1024;
      char* lB = reinterpret_cast<char*>(Bsm) + b * 16384 + t * 8192 + wid * 1024;
      __builtin_amdgcn_global_load_lds((gptr_t)ga, (lptr_t)lA, 16, 0, 0);
      __builtin_amdgcn_global_load_lds((gptr_t)gb, (lptr_t)lB, 16, 0, 0);
    }
  };

  stage(0, 0);
  __syncthreads();
  const int xorv = (lane & 7) << 4;
  for (int kt = 0; kt < 4; ++kt) {
    if (kt < 3) stage(kt + 1, (kt + 1) & 1);  // prefetch before compute
    const char* Ab = reinterpret_cast<const char*>(Asm) + (kt & 1) * 16384;
    const char* Bb = reinterpret_cast<const char*>(Bsm) + (kt & 1) * 16384;
#pragma unroll
    for (int kk = 0; kk < 2; ++kk) {
      bf16x8 af[4], bfr[2];
      const int kcolb = (kk * 32 + (lane >> 4) * 8) * 2;
      const int arow = wr * 64 + (lane & 15);
      const int brow = wc * 32 + (lane & 15);
#pragma unroll
      for (int m = 0; m < 4; ++m)
        af[m] = *reinterpret_cast<const bf16x8*>(
            Ab + ((((arow + m * 16) << 7) + kcolb) ^ xorv));
#pragma unroll
      for (int n = 0; n < 2; ++n)
        bfr[n] = *reinterpret_cast<const bf16x8*>(
            Bb + ((((brow + n * 16) << 7) + kcolb) ^ xorv));
#pragma unroll
      for (int m = 0; m < 4; ++m)
#pragma unroll
        for (int n = 0; n < 2; ++n)
          acc[m][n] = __builtin_amdgcn_mfma_f32_16x16x32_bf16(
              af[m], bfr[n], acc[m][n], 0, 0, 0);
    }
    __syncthreads();  // one barrier per kt (drains this kt's prefetch late)
  }

  // ---- epilogue: exp + intra-block LDS reduction (unchanged from R6)
  float colpart[2] = {0.0f, 0.0f};
#pragma unroll
  for (int m = 0; m < 4; ++m) {
#pragma unroll
    for (int v = 0; v < 4; ++v) {
      const int lrow = wr * 64 + m * 16 + (lane >> 4) * 4 + v;
      const int gi = rowBase + lrow;
      float rowpart = 0.0f;
#pragma unroll
      for (int n = 0; n < 2; ++n) {
        const float d = acc[m][n][v];
        float val = exp2f(d * E2SCALE);
        if (isdiag) {
          const int gj = colBase + wc * 32 + n * 16 + (lane & 15);
          if (gi == gj) val = 0.0f;
        } else if (ispos) {
          const int gj = colBase + wc * 32 + n * 16 + (lane & 15);
          if (gj == gi + HALF_B) {
            const float pv = d * INV_T;
            pos[gi] = pv;
            pos[gj] = pv;
          }
        }
        rowpart += val;
        colpart[n] += val;
      }
      rowpart += __shfl_xor(rowpart, 1);
      rowpart += __shfl_xor(rowpart, 2);
      rowpart += __shfl_xor(rowpart, 4);
      rowpart += __shfl_xor(rowpart, 8);
      if ((lane & 15) == 0) atomicAdd(&rowbuf[lrow], rowpart);
    }
  }
  if (!isdiag) {
#pragma unroll
    for (int n = 0; n < 2; ++n) {
      float c = colpart[n];
      c += __shfl_xor(c, 16);
      c += __shfl_xor(c, 32);
      if (lane < 16) atomicAdd(&colbuf[wc * 32 + n * 16 + lane], c);
    }
  }
  __syncthreads();

  if (tid < 128) {
    P[(size_t)bx * NROW + rowBase + tid] = rowbuf[tid];
  } else if (tid < 256 && !isdiag) {
    P[(size_t)by * NROW + colBase + tid - 128] = colbuf[tid - 128];
  }
}

// ---------------- kernel 3: row reduction + per-row log term ----------------
__global__ __launch_bounds__(256) void rowreduce_kernel(
    const float* __restrict__ P, const float* __restrict__ pos,
    float* __restrict__ loss_accum) {
  const int i = blockIdx.x * 256 + threadIdx.x;
  float s = 0.0f;
#pragma unroll 8
  for (int k = 0; k < NB; ++k) s += P[(size_t)k * NROW + i];
  float partial = logf(s) - pos[i];
#pragma unroll
  for (int m = 32; m; m >>= 1) partial += __shfl_xor(partial, m);
  __shared__ float sred[4];
  if ((threadIdx.x & 63) == 0) sred[threadIdx.x >> 6] = partial;
  __syncthreads();
  if (threadIdx.x == 0)
    atomicAdd(loss_accum, sred[0] + sred[1] + sred[2] + sred[3]);
}

// ---------------- kernel 4: finalize ----------------
__global__ void finalize_kernel(const float* __restrict__ loss_accum,
                                float* __restrict__ out) {
  out[0] = loss_accum[0] * (1.0f / (float)NROW);
}

extern "C" void kernel_launch(void* const* d_in, const int* in_sizes, int n_in,
                              void* d_out, int out_size, void* d_ws, size_t ws_size,
                              hipStream_t stream) {
  const float* z_i = (const float*)d_in[0];
  const float* z_j = (const float*)d_in[1];
  float* out = (float*)d_out;

  char* ws = (char*)d_ws;
  __hip_bfloat16* zn = (__hip_bfloat16*)ws;                      // 4 MB
  float* pos  = (float*)(ws + 4194304);                          // 32 KB
  float* P    = (float*)(ws + 4194304 + 32768);                  // 2 MB
  float* lacc = (float*)(ws + 4194304 + 32768 + 2097152);        // 4 B

  normalize_kernel<<<512, 256, 0, stream>>>(z_i, z_j, zn, (float4*)P, lacc);
  gram_abl_kernel<<<NTILES, 512, 0, stream>>>(zn);      // DIAGNOSTIC dispatch
  gram_kernel<<<NTILES, 512, 0, stream>>>(zn, P, pos);  // real
  rowreduce_kernel<<<NROW / 256, 256, 0, stream>>>(P, pos, lacc);
  finalize_kernel<<<1, 1, 0, stream>>>(lacc, out);
}

// Round 8
// 47.826 us; speedup vs baseline: 1.7381x; 1.7381x over previous
//
#include <hip/hip_runtime.h>
#include <hip/hip_bf16.h>

typedef __attribute__((ext_vector_type(8))) short bf16x8;
typedef __attribute__((ext_vector_type(4))) float f32x4;

typedef const __attribute__((address_space(1))) void* gptr_t;
typedef __attribute__((address_space(3))) void* lptr_t;

#define NROW 8192
#define DDIM 256
#define HALF_B 4096
#define NB 64                        // 8192/128 tile bands
#define NTILES (NB * (NB + 1) / 2)   // 2080 upper-triangle tiles

// exp(dot/T) = exp2(dot * log2(e)/T), T = 0.07
#define E2SCALE 20.6099291555566196f
#define INV_T   14.2857142857142858f

// ---------------- kernel 1: row-normalize + bf16 cast + zero lacc -----------
__global__ __launch_bounds__(256) void normalize_kernel(
    const float* __restrict__ z_i, const float* __restrict__ z_j,
    __hip_bfloat16* __restrict__ zn, float* __restrict__ loss_accum) {
  const int lane = threadIdx.x & 63;
  const int w = blockIdx.x * 4 + (threadIdx.x >> 6);  // wave id 0..2047
  for (int row = w; row < NROW; row += 2048) {
    const float* src = (row < HALF_B) ? (z_i + (size_t)row * DDIM)
                                      : (z_j + (size_t)(row - HALF_B) * DDIM);
    float4 v = *reinterpret_cast<const float4*>(src + lane * 4);
    float ss = v.x * v.x + v.y * v.y + v.z * v.z + v.w * v.w;
#pragma unroll
    for (int m = 32; m; m >>= 1) ss += __shfl_xor(ss, m);
    float inv = 1.0f / sqrtf(ss);
    ushort4 o;
    {
      __hip_bfloat16 h;
      h = __float2bfloat16(v.x * inv); o.x = *reinterpret_cast<unsigned short*>(&h);
      h = __float2bfloat16(v.y * inv); o.y = *reinterpret_cast<unsigned short*>(&h);
      h = __float2bfloat16(v.z * inv); o.z = *reinterpret_cast<unsigned short*>(&h);
      h = __float2bfloat16(v.w * inv); o.w = *reinterpret_cast<unsigned short*>(&h);
    }
    *reinterpret_cast<ushort4*>(zn + (size_t)row * DDIM + lane * 4) = o;
  }
  if (blockIdx.x == 0 && threadIdx.x == 0) *loss_accum = 0.0f;
}

// ---------------- kernel 2: upper-triangle 128x128 Gram tiles ---------------
// 512 thr = 8 waves (2 row x 4 col), wave-tile 64x32 (acc[4][2]).
// Single-buffer LDS staging (R6 loop — dbuf regressed occupancy in R7).
// NEW epilogue (R7 ablation: old shfl/atomic epilogue was 38us of 52):
//   per (m,v): lane's 2-col partial -> ONE ds_write into rowmat[128][68]
//   colparts (register-axis, free) -> colmat[128][9]
//   barrier, then read-reduce: 512 thr x 4xb128 + 2 shfl -> P[bx][rows];
//   thr<128 sum colmat -> P[by][cols]. No shfl chains, no LDS atomics.
// rowmat/colmat alias the staging LDS (free after last barrier).
__global__ __launch_bounds__(512, 4) void gram_kernel(
    const __hip_bfloat16* __restrict__ zn,
    float* __restrict__ P, float* __restrict__ pos) {
  __shared__ char smem[39424];   // stage: A 16K @0, B 16K @16384
                                 // rowmat[128][68] f32 @0 (34816 B)
                                 // colmat[128][9]  f32 @34816 (4608 B)
  __hip_bfloat16* Asm = (__hip_bfloat16*)smem;
  __hip_bfloat16* Bsm = (__hip_bfloat16*)(smem + 16384);
  float (*rowmat)[68] = (float (*)[68])smem;
  float (*colmat)[9]  = (float (*)[9])(smem + 34816);

  const int tid = threadIdx.x;
  const int lane = tid & 63;
  const int wid = tid >> 6;          // 0..7
  const int wr = wid >> 2;           // wave row 0..1 (64 rows each)
  const int wc = wid & 3;            // wave col 0..3 (32 cols each)

  int p = blockIdx.x;
  int by = 0;
  while (p >= NB - by) { p -= NB - by; ++by; }
  const int bx = by + p;
  const int rowBase = by * 128;
  const int colBase = bx * 128;
  const bool isdiag = (bx == by);
  const bool ispos = (bx - by == 32);

  f32x4 acc[4][2] = {};
  const int csw = ((tid & 7) ^ ((tid >> 3) & 7)) * 8;  // pre-swizzled src col
  const int rloc = tid >> 3;

  for (int kt = 0; kt < 4; ++kt) {   // K = 256, BK = 64
#pragma unroll
    for (int t = 0; t < 2; ++t) {
      const int r = t * 64 + rloc;
      const __hip_bfloat16* ga = zn + (size_t)(rowBase + r) * DDIM + kt * 64 + csw;
      const __hip_bfloat16* gb = zn + (size_t)(colBase + r) * DDIM + kt * 64 + csw;
      char* lA = reinterpret_cast<char*>(Asm) + t * 8192 + wid * 1024;
      char* lB = reinterpret_cast<char*>(Bsm) + t * 8192 + wid * 1024;
      __builtin_amdgcn_global_load_lds((gptr_t)ga, (lptr_t)lA, 16, 0, 0);
      __builtin_amdgcn_global_load_lds((gptr_t)gb, (lptr_t)lB, 16, 0, 0);
    }
    __syncthreads();

    const char* Ab = reinterpret_cast<const char*>(Asm);
    const char* Bb = reinterpret_cast<const char*>(Bsm);
    const int xorv = (lane & 7) << 4;
#pragma unroll
    for (int kk = 0; kk < 2; ++kk) {
      bf16x8 af[4], bfr[2];
      const int kcolb = (kk * 32 + (lane >> 4) * 8) * 2;
      const int arow = wr * 64 + (lane & 15);
      const int brow = wc * 32 + (lane & 15);
#pragma unroll
      for (int m = 0; m < 4; ++m)
        af[m] = *reinterpret_cast<const bf16x8*>(
            Ab + ((((arow + m * 16) << 7) + kcolb) ^ xorv));
#pragma unroll
      for (int n = 0; n < 2; ++n)
        bfr[n] = *reinterpret_cast<const bf16x8*>(
            Bb + ((((brow + n * 16) << 7) + kcolb) ^ xorv));
#pragma unroll
      for (int m = 0; m < 4; ++m)
#pragma unroll
        for (int n = 0; n < 2; ++n)
          acc[m][n] = __builtin_amdgcn_mfma_f32_16x16x32_bf16(
              af[m], bfr[n], acc[m][n], 0, 0, 0);
    }
    __syncthreads();   // after last kt: all ds_reads done, staging LDS free
  }

  // ---- epilogue phase 1: exp + scatter partials to LDS (no shfl, no atomic)
  // C/D layout: col = lane&15, row = (lane>>4)*4 + v
  float colpart[2] = {0.0f, 0.0f};
#pragma unroll
  for (int m = 0; m < 4; ++m) {
#pragma unroll
    for (int v = 0; v < 4; ++v) {
      const int lrow = wr * 64 + m * 16 + (lane >> 4) * 4 + v;
      const int gi = rowBase + lrow;
      float rp = 0.0f;
#pragma unroll
      for (int n = 0; n < 2; ++n) {
        const float d = acc[m][n][v];
        float val = exp2f(d * E2SCALE);
        if (isdiag) {
          const int gj = colBase + wc * 32 + n * 16 + (lane & 15);
          if (gi == gj) val = 0.0f;           // exclude diagonal
        } else if (ispos) {
          const int gj = colBase + wc * 32 + n * 16 + (lane & 15);
          if (gj == gi + HALF_B) {            // positive pair
            const float pv = d * INV_T;
            pos[gi] = pv;
            pos[gj] = pv;
          }
        }
        rp += val;
        colpart[n] += val;
      }
      rowmat[lrow][wc * 16 + (lane & 15)] = rp;
    }
  }
  colmat[wc * 32 + (lane & 15)][wr * 4 + (lane >> 4)] = colpart[0];
  colmat[wc * 32 + 16 + (lane & 15)][wr * 4 + (lane >> 4)] = colpart[1];
  __syncthreads();

  // ---- epilogue phase 2: read-reduce + coalesced P stores
  {
    const int row = tid >> 2;          // 0..127
    const int seg = tid & 3;           // 0..3 (16 cols each)
    const float* rr = &rowmat[row][seg * 16];
    f32x4 a0 = *reinterpret_cast<const f32x4*>(rr);
    f32x4 a1 = *reinterpret_cast<const f32x4*>(rr + 4);
    f32x4 a2 = *reinterpret_cast<const f32x4*>(rr + 8);
    f32x4 a3 = *reinterpret_cast<const f32x4*>(rr + 12);
    f32x4 t4 = (a0 + a1) + (a2 + a3);
    float s = (t4[0] + t4[1]) + (t4[2] + t4[3]);
    s += __shfl_xor(s, 1);
    s += __shfl_xor(s, 2);
    if (seg == 0) P[(size_t)bx * NROW + rowBase + row] = s;
  }
  if (tid < 128 && !isdiag) {
    const float* cc = colmat[tid];
    float s = ((cc[0] + cc[1]) + (cc[2] + cc[3])) +
              ((cc[4] + cc[5]) + (cc[6] + cc[7]));
    P[(size_t)by * NROW + colBase + tid] = s;
  }
}

// ---------------- kernel 3: row reduction + per-row log term ----------------
__global__ __launch_bounds__(256) void rowreduce_kernel(
    const float* __restrict__ P, const float* __restrict__ pos,
    float* __restrict__ loss_accum) {
  const int i = blockIdx.x * 256 + threadIdx.x;
  float s = 0.0f;
#pragma unroll 8
  for (int k = 0; k < NB; ++k) s += P[(size_t)k * NROW + i];
  float partial = logf(s) - pos[i];
#pragma unroll
  for (int m = 32; m; m >>= 1) partial += __shfl_xor(partial, m);
  __shared__ float sred[4];
  if ((threadIdx.x & 63) == 0) sred[threadIdx.x >> 6] = partial;
  __syncthreads();
  if (threadIdx.x == 0)
    atomicAdd(loss_accum, sred[0] + sred[1] + sred[2] + sred[3]);
}

// ---------------- kernel 4: finalize ----------------
__global__ void finalize_kernel(const float* __restrict__ loss_accum,
                                float* __restrict__ out) {
  out[0] = loss_accum[0] * (1.0f / (float)NROW);
}

extern "C" void kernel_launch(void* const* d_in, const int* in_sizes, int n_in,
                              void* d_out, int out_size, void* d_ws, size_t ws_size,
                              hipStream_t stream) {
  const float* z_i = (const float*)d_in[0];
  const float* z_j = (const float*)d_in[1];
  float* out = (float*)d_out;

  char* ws = (char*)d_ws;
  __hip_bfloat16* zn = (__hip_bfloat16*)ws;                      // 4 MB
  float* pos  = (float*)(ws + 4194304);                          // 32 KB
  float* P    = (float*)(ws + 4194304 + 32768);                  // 2 MB
  float* lacc = (float*)(ws + 4194304 + 32768 + 2097152);        // 4 B

  normalize_kernel<<<512, 256, 0, stream>>>(z_i, z_j, zn, lacc);
  gram_kernel<<<NTILES, 512, 0, stream>>>(zn, P, pos);
  rowreduce_kernel<<<NROW / 256, 256, 0, stream>>>(P, pos, lacc);
  finalize_kernel<<<1, 1, 0, stream>>>(lacc, out);
}